// Round 23
// baseline (385.274 us; speedup 1.0000x reference)
//
#include <hip/hip_runtime.h>
#include <math.h>

#define LSEQ 624
#define NPG_C 1249
#define BATCH_C 64
#define NROWS (BATCH_C*LSEQ)          // 39936
#define N_NODES_C 79936
#define N_EDGES_C 639488
#define DIP 1160
#define DIN 512
#define CDIM 640
#define NH 8
#define HD 64
#define DS 64
#define CAP 96
#define TCH 48
#define NCHK 13
#define HSLOT 2097152                  // 64*8*4096 elements per h_start slot

// workspace layout (float offsets)
#define OFF_CHK   0
#define OFF_WF    638976
#define OFF_BF    657536
#define OFF_WOP   658944
#define OFF_BOP   667136
#define OFF_XBC   667392
#define OFF_DTV   26226432
#define OFF_EV    26545920
#define OFF_YS    26865408
#define OFF_FEAT  47312640
#define OFF_AGG   48591616
#define OFF_ECUM  (OFF_AGG + 2000000)
#define OFF_BBF   (OFF_AGG + 2400000)  // bf16 B mirror
#define OFF_WOPT  (OFF_AGG + 4000000)  // WopT[16][512], dead before k_agg2
#define OFF_PROJ  (OFF_XBC + 8000000)  // bf16 pmsg

typedef __attribute__((ext_vector_type(8))) short bf16x8;
typedef __attribute__((ext_vector_type(4))) float f32x4;

__device__ __forceinline__ float siluf(float x) {
    return x / (1.f + __expf(-x));
}

__device__ __forceinline__ unsigned short f2bf(float f) {
    unsigned int u = __float_as_uint(f);
    u += 0x7fffu + ((u >> 16) & 1u);
    return (unsigned short)(u >> 16);
}
__device__ __forceinline__ float bf2f(unsigned short h) {
    return __uint_as_float(((unsigned int)h) << 16);
}

// hst layout: bf16, [p][n]
__device__ __forceinline__ unsigned short* hstp(unsigned short* hst, int c, int b, int head) {
    return hst + (size_t)(c - 1) * HSLOT + (size_t)(b * NH + head) * 4096;
}

// gather check-node rows
__global__ void k_gather(const float* __restrict__ ni, float* __restrict__ chk) {
    int gid = blockIdx.x * 256 + threadIdx.x;
    if (gid >= NROWS * 16) return;
    int row = gid >> 4, k = gid & 15;
    int node = (row / LSEQ) * NPG_C + (row % LSEQ);
    chk[gid] = ni[node * 16 + k];
}

// fused weights (+ WopT emission)
__global__ void k_fusew(const float* __restrict__ We, const float* __restrict__ be,
                        const float* __restrict__ Wi, const float* __restrict__ bi,
                        const float* __restrict__ Wo, const float* __restrict__ bo,
                        const float* __restrict__ Wp, const float* __restrict__ bp,
                        float* __restrict__ Wf, float* __restrict__ bf,
                        float* __restrict__ Wop, float* __restrict__ bop,
                        float* __restrict__ WopT) {
    int id = blockIdx.x * 256 + threadIdx.x;
    if (id < 16 * DIP) {
        int i = id / DIP, j = id % DIP;
        float s = 0.f;
        for (int k = 0; k < 256; k++) s = fmaf(We[i * 256 + k], Wi[k * DIP + j], s);
        Wf[id] = s;
    } else if (id < 16 * DIP + DIP) {
        int j = id - 16 * DIP;
        float s = bi[j];
        for (int k = 0; k < 256; k++) s = fmaf(be[k], Wi[k * DIP + j], s);
        bf[j] = s;
    } else if (id < 16 * DIP + DIP + DIN * 16) {
        int id2 = id - (16 * DIP + DIP);
        int c = id2 >> 4, o = id2 & 15;
        float s = 0.f;
        for (int k = 0; k < 256; k++) s = fmaf(Wo[c * 256 + k], Wp[k * 16 + o], s);
        Wop[id2] = s;
    } else if (id < 16 * DIP + DIP + DIN * 16 + 16) {
        int o = id - (16 * DIP + DIP + DIN * 16);
        float s = bp[o];
        for (int k = 0; k < 256; k++) s = fmaf(bo[k], Wp[k * 16 + o], s);
        bop[o] = s;
    } else if (id < 16 * DIP + DIP + DIN * 16 + 16 + 16 * DIN) {
        int id2 = id - (16 * DIP + DIP + DIN * 16 + 16);
        int o = id2 >> 9, c = id2 & 511;
        float s = 0.f;
        for (int k = 0; k < 256; k++) s = fmaf(Wo[c * 256 + k], Wp[k * 16 + o], s);
        WopT[id2] = s;
    }
}

// fused in_proj(xBC cols) + causal depthwise conv + silu; emits bf16 B mirror
__global__ __launch_bounds__(320) void k_conv(const float* __restrict__ chk,
        const float* __restrict__ Wf, const float* __restrict__ bf,
        const float* __restrict__ cw, const float* __restrict__ cb,
        float* __restrict__ xBCc, unsigned short* __restrict__ bbf) {
    int c = blockIdx.x * 320 + threadIdx.x;
    int t0 = blockIdx.y * 78;
    int b = blockIdx.z;
    float w[16];
#pragma unroll
    for (int k = 0; k < 16; k++) w[k] = Wf[k * DIP + DIN + c];
    float bfx = bf[DIN + c];
    float k0 = cw[c * 4 + 0], k1 = cw[c * 4 + 1], k2 = cw[c * 4 + 2], k3 = cw[c * 4 + 3];
    float cbv = cb[c];
    const float* crow = chk + (size_t)(b * LSEQ) * 16;
    float* out = xBCc + (size_t)(b * LSEQ) * CDIM + c;
    int isB = (c >= 512 && c < 576);
    unsigned short* bout = bbf + (size_t)(b * LSEQ) * 64 + (c - 512);

    float w0 = 0.f, w1 = 0.f, w2 = 0.f;
#pragma unroll
    for (int d = 3; d >= 1; d--) {
        int tau = t0 - d;
        float s = 0.f;
        if (tau >= 0) {
            s = bfx;
            const float* cr = crow + tau * 16;
#pragma unroll
            for (int k = 0; k < 16; k++) s = fmaf(cr[k], w[k], s);
        }
        if (d == 3) w0 = s; else if (d == 2) w1 = s; else w2 = s;
    }
    for (int t = t0; t < t0 + 78; t++) {
        const float* cr = crow + t * 16;
        float w3 = bfx;
#pragma unroll
        for (int k = 0; k < 16; k++) w3 = fmaf(cr[k], w[k], w3);
        float a = fmaf(k0, w0, fmaf(k1, w1, fmaf(k2, w2, fmaf(k3, w3, cbv))));
        float v = siluf(a);
        out[(size_t)t * CDIM] = v;
        if (isB) bout[(size_t)t * 64] = f2bf(v);
        w0 = w1; w1 = w2; w2 = w3;
    }
}

// fused dt + within-chunk prefix
__global__ __launch_bounds__(256) void k_dte(const float* __restrict__ chk,
        const float* __restrict__ Wf, const float* __restrict__ bf,
        const float* __restrict__ A_log, const float* __restrict__ dt_bias,
        float* __restrict__ dtv, float* __restrict__ ecum) {
    int s = blockIdx.x * 4 + (threadIdx.x >> 6);
    int lane = threadIdx.x & 63;
    int h = s & 7;
    int cb = s >> 3;
    int c = cb % NCHK, b = cb / NCHK;
    int r0 = b * LSEQ + c * TCH;
    float wcol[16];
#pragma unroll
    for (int k = 0; k < 16; k++) wcol[k] = Wf[k * DIP + DIN + CDIM + h];
    float base = bf[DIN + CDIM + h] + dt_bias[h];
    float nA = -__expf(A_log[h]);
    float v = 0.f, sp = 0.f;
    if (lane < TCH) {
        const float* cr = chk + (size_t)(r0 + lane) * 16;
        float acc = base;
#pragma unroll
        for (int k = 0; k < 16; k++) acc = fmaf(cr[k], wcol[k], acc);
        sp = (acc > 20.f) ? acc : log1pf(__expf(acc));
        v = nA * sp;
    }
#pragma unroll
    for (int off = 1; off < 64; off <<= 1) {
        float u = __shfl_up(v, off);
        if (lane >= off) v += u;
    }
    if (lane < TCH) {
        dtv[(size_t)(r0 + lane) * NH + h] = sp;
        ecum[(size_t)(r0 + lane) * NH + h] = v;
    }
}

// G[t][s] = C_t . B_s per (b,chunk)
__global__ __launch_bounds__(256) void k_gmat(const float* __restrict__ xBCc,
        float* __restrict__ Gm) {
    int c = blockIdx.x, b = blockIdx.y;
    int tid = threadIdx.x;
    int bs = b * LSEQ;
    __shared__ __align__(16) float sBC[TCH * 132];
#pragma unroll
    for (int j = 0; j < 6; j++) {
        int g = j * 256 + tid;
        int f = g * 4;
        int t = f >> 7, col = f & 127;
        float4 v = *(const float4*)(xBCc + (size_t)(bs + c * TCH + t) * CDIM + 512 + col);
        *(float4*)&sBC[t * 132 + col] = v;
    }
    __syncthreads();
    int t0 = (tid >> 4) * 3, s0 = (tid & 15) * 3;
    float acc[3][3];
#pragma unroll
    for (int i = 0; i < 3; i++)
#pragma unroll
        for (int j = 0; j < 3; j++) acc[i][j] = 0.f;
    for (int k = 0; k < 64; k++) {
        float c0 = sBC[(t0 + 0) * 132 + 64 + k];
        float c1 = sBC[(t0 + 1) * 132 + 64 + k];
        float c2 = sBC[(t0 + 2) * 132 + 64 + k];
        float b0 = sBC[(s0 + 0) * 132 + k];
        float b1 = sBC[(s0 + 1) * 132 + k];
        float b2 = sBC[(s0 + 2) * 132 + k];
        acc[0][0] = fmaf(c0, b0, acc[0][0]); acc[0][1] = fmaf(c0, b1, acc[0][1]); acc[0][2] = fmaf(c0, b2, acc[0][2]);
        acc[1][0] = fmaf(c1, b0, acc[1][0]); acc[1][1] = fmaf(c1, b1, acc[1][1]); acc[1][2] = fmaf(c1, b2, acc[1][2]);
        acc[2][0] = fmaf(c2, b0, acc[2][0]); acc[2][1] = fmaf(c2, b1, acc[2][1]); acc[2][2] = fmaf(c2, b2, acc[2][2]);
    }
    size_t gb = (size_t)(b * NCHK + c) * (TCH * TCH);
#pragma unroll
    for (int i = 0; i < 3; i++)
#pragma unroll
        for (int j = 0; j < 3; j++)
            Gm[gb + (t0 + i) * TCH + (s0 + j)] = acc[i][j];
}

// MFMA state carry: grid (8,64); wave wv owns p-tile; acc = h state.
__global__ __launch_bounds__(256) void k_scarry(const float* __restrict__ xBCc,
        const unsigned short* __restrict__ bbf,
        const float* __restrict__ dtv, const float* __restrict__ ecum,
        unsigned short* __restrict__ hst) {
    int head = blockIdx.x, b = blockIdx.y;
    int tid = threadIdx.x;
    int lane = tid & 63, wv = tid >> 6;
    int bs = b * LSEQ;
    __shared__ unsigned short sXh[64 * 72];
    __shared__ unsigned short sXl[64 * 72];
    __shared__ unsigned short sBn[64 * 72];

    int colL = lane & 15;
    int rbase = (lane >> 4) * 4;
    int kfrag = 8 * (lane >> 4);

    f32x4 acc[4] = { {0,0,0,0}, {0,0,0,0}, {0,0,0,0}, {0,0,0,0} };

    float4 rX[3];
    ushort4 rBu[3];
    float rEc[3], rDt[3], rEcL = 0.f;

#define SC_ISSUE(cc)                                                                \
    {                                                                               \
        int r0i = bs + (cc) * TCH;                                                  \
        _Pragma("unroll")                                                           \
        for (int jj = 0; jj < 3; jj++) {                                            \
            int g = jj * 256 + tid; int t = g >> 4; int col = (g & 15) * 4;         \
            rX[jj] = *(const float4*)(xBCc + (size_t)(r0i + t) * CDIM + head * HD + col); \
            rBu[jj] = *(const ushort4*)(bbf + (size_t)(r0i + t) * 64 + col);        \
            rEc[jj] = ecum[(size_t)(r0i + t) * NH + head];                          \
            rDt[jj] = dtv[(size_t)(r0i + t) * NH + head];                           \
        }                                                                           \
        rEcL = ecum[(size_t)(r0i + TCH - 1) * NH + head];                           \
    }

    {
        int p = tid >> 2, k4 = 48 + (tid & 3) * 4;
        ushort4 z = { 0, 0, 0, 0 };
        *(ushort4*)&sXh[p * 72 + k4] = z;
        *(ushort4*)&sXl[p * 72 + k4] = z;
        *(ushort4*)&sBn[p * 72 + k4] = z;
    }

    SC_ISSUE(0);
    for (int c = 0; c < NCHK; c++) {
        __syncthreads();
        float eL = __expf(rEcL);
#pragma unroll
        for (int jj = 0; jj < 3; jj++) {
            int g = jj * 256 + tid;
            int t = g >> 4, col = (g & 15) * 4;
            float w = __expf(rEcL - rEc[jj]) * rDt[jj];
            float m0 = w * rX[jj].x, m1 = w * rX[jj].y;
            float m2 = w * rX[jj].z, m3 = w * rX[jj].w;
            unsigned short h0 = f2bf(m0), h1 = f2bf(m1), h2 = f2bf(m2), h3 = f2bf(m3);
            sXh[(col + 0) * 72 + t] = h0;
            sXh[(col + 1) * 72 + t] = h1;
            sXh[(col + 2) * 72 + t] = h2;
            sXh[(col + 3) * 72 + t] = h3;
            sXl[(col + 0) * 72 + t] = f2bf(m0 - bf2f(h0));
            sXl[(col + 1) * 72 + t] = f2bf(m1 - bf2f(h1));
            sXl[(col + 2) * 72 + t] = f2bf(m2 - bf2f(h2));
            sXl[(col + 3) * 72 + t] = f2bf(m3 - bf2f(h3));
            sBn[(col + 0) * 72 + t] = rBu[jj].x;
            sBn[(col + 1) * 72 + t] = rBu[jj].y;
            sBn[(col + 2) * 72 + t] = rBu[jj].z;
            sBn[(col + 3) * 72 + t] = rBu[jj].w;
        }
        __syncthreads();
        if (c + 1 < NCHK) SC_ISSUE(c + 1);

        if (c > 0) {
            unsigned short* hp = hstp(hst, c, b, head);
#pragma unroll
            for (int nt = 0; nt < 4; nt++)
#pragma unroll
                for (int r = 0; r < 4; r++)
                    hp[(wv * 16 + rbase + r) * 64 + nt * 16 + colL] = f2bf(acc[nt][r]);
        }
#pragma unroll
        for (int nt = 0; nt < 4; nt++)
#pragma unroll
            for (int r = 0; r < 4; r++)
                acc[nt][r] *= eL;
#pragma unroll
        for (int ks = 0; ks < 64; ks += 32) {
            bf16x8 ah = *(const bf16x8*)&sXh[(wv * 16 + colL) * 72 + ks + kfrag];
            bf16x8 al = *(const bf16x8*)&sXl[(wv * 16 + colL) * 72 + ks + kfrag];
#pragma unroll
            for (int nt = 0; nt < 4; nt++) {
                bf16x8 bb = *(const bf16x8*)&sBn[(nt * 16 + colL) * 72 + ks + kfrag];
                acc[nt] = __builtin_amdgcn_mfma_f32_16x16x32_bf16(ah, bb, acc[nt], 0, 0, 0);
                acc[nt] = __builtin_amdgcn_mfma_f32_16x16x32_bf16(al, bb, acc[nt], 0, 0, 0);
            }
        }
    }
#undef SC_ISSUE
}

// intra-chunk + fused y-correction via bf16 MFMA.
__global__ __launch_bounds__(256) void k_intra(float* __restrict__ xBCc,
        const float* __restrict__ Gm, const float* __restrict__ dtv,
        const float* __restrict__ ecum, const float* __restrict__ Dskip,
        const unsigned short* __restrict__ hst) {
    int bid = blockIdx.x;
    int xcd = bid & 7;
    int head = (bid >> 3) & 7;
    int g = (bid >> 6) * 8 + xcd;
    int c = g % NCHK, b = g / NCHK;
    int tid = threadIdx.x;
    int lane = tid & 63;
    int wv = tid >> 6;
    int bs = b * LSEQ;
    int r0 = bs + c * TCH;

    __shared__ __align__(16) unsigned char smraw[35904];
    float* sXf = (float*)(smraw);
    unsigned short* sMh = (unsigned short*)(smraw + 12288);
    unsigned short* sMl = (unsigned short*)(smraw + 19200);
    unsigned short* sCt = (unsigned short*)(smraw + 19200);
    unsigned short* sXh = (unsigned short*)(smraw + 26112);
    unsigned short* sHt = (unsigned short*)(smraw + 26112);
    float* sE  = (float*)(smraw + 35328);
    float* sEx = (float*)(smraw + 35520);
    float* sdt = (float*)(smraw + 35712);

    ushort4 rHu[4];
    if (c > 0) {
        const unsigned short* hp = hstp((unsigned short*)hst, c, b, head);
#pragma unroll
        for (int j = 0; j < 4; j++)
            rHu[j] = *(const ushort4*)(hp + 4 * (j * 256 + tid));
    }

    ushort4 rCu[3];
#pragma unroll
    for (int j = 0; j < 3; j++) {
        int g2 = j * 256 + tid;
        int t = g2 >> 4, col = (g2 & 15) * 4;
        const float* rowp = xBCc + (size_t)(r0 + t) * CDIM;
        float4 xv = *(const float4*)(rowp + head * HD + col);
        *(float4*)&sXf[t * 64 + col] = xv;
        float4 cv = *(const float4*)(rowp + 576 + col);
        ushort4 cu = { f2bf(cv.x), f2bf(cv.y), f2bf(cv.z), f2bf(cv.w) };
        rCu[j] = cu;
    }
    if (tid < TCH) {
        float e = ecum[(size_t)(r0 + tid) * NH + head];
        sE[tid] = e;
        sEx[tid] = __expf(e);
        sdt[tid] = dtv[(size_t)(r0 + tid) * NH + head];
    }
    __syncthreads();

    size_t gb = (size_t)(b * NCHK + c) * (TCH * TCH);
#pragma unroll
    for (int k = 0; k < 9; k++) {
        int id = k * 256 + tid;
        int t = id / TCH, s = id - t * TCH;
        float gv = Gm[gb + id];
        float m = (s <= t) ? __expf(sE[t] - sE[s]) * sdt[s] * gv : 0.f;
        unsigned short mh = f2bf(m);
        sMh[t * 72 + s] = mh;
        sMl[t * 72 + s] = f2bf(m - bf2f(mh));
    }
    for (int w = tid; w < 768; w += 256) {
        int t = w >> 4, s = 48 + (w & 15);
        sMh[t * 72 + s] = 0;
        sMl[t * 72 + s] = 0;
    }
#pragma unroll
    for (int i = 0; i < 3; i++) {
        int w = i * 256 + tid;
        int p = w & 63, k4 = (w >> 6) * 4;
        float v0 = sXf[(k4 + 0) * 64 + p];
        float v1 = sXf[(k4 + 1) * 64 + p];
        float v2 = sXf[(k4 + 2) * 64 + p];
        float v3 = sXf[(k4 + 3) * 64 + p];
        ushort4 hi = { f2bf(v0), f2bf(v1), f2bf(v2), f2bf(v3) };
        *(ushort4*)&sXh[p * 72 + k4] = hi;
    }
    {
        int p = tid >> 2, k4 = 48 + (tid & 3) * 4;
        ushort4 z = { 0, 0, 0, 0 };
        *(ushort4*)&sXh[p * 72 + k4] = z;
    }
    __syncthreads();

    int pt = wv * 16;
    int colL = lane & 15;
    int rbase = (lane >> 4) * 4;
    int kfrag = 8 * (lane >> 4);

    float xo[3][4];
#pragma unroll
    for (int tt = 0; tt < 3; tt++)
#pragma unroll
        for (int r = 0; r < 4; r++)
            xo[tt][r] = sXf[(tt * 16 + rbase + r) * 64 + pt + colL];

    f32x4 acc[3] = { {0,0,0,0}, {0,0,0,0}, {0,0,0,0} };
    f32x4 acc2[3] = { {0,0,0,0}, {0,0,0,0}, {0,0,0,0} };
#pragma unroll
    for (int ks = 0; ks < 64; ks += 32) {
        bf16x8 bh = *(const bf16x8*)&sXh[(pt + colL) * 72 + ks + kfrag];
#pragma unroll
        for (int tt = 0; tt < 3; tt++) {
            bf16x8 ah = *(const bf16x8*)&sMh[(tt * 16 + colL) * 72 + ks + kfrag];
            bf16x8 al = *(const bf16x8*)&sMl[(tt * 16 + colL) * 72 + ks + kfrag];
            acc[tt] = __builtin_amdgcn_mfma_f32_16x16x32_bf16(ah, bh, acc[tt], 0, 0, 0);
            acc[tt] = __builtin_amdgcn_mfma_f32_16x16x32_bf16(al, bh, acc[tt], 0, 0, 0);
        }
    }
    __syncthreads();
#pragma unroll
    for (int j = 0; j < 3; j++) {
        int g2 = j * 256 + tid;
        int t = g2 >> 4, col = (g2 & 15) * 4;
        *(ushort4*)&sCt[t * 72 + col] = rCu[j];
    }
    if (c > 0) {
#pragma unroll
        for (int j = 0; j < 4; j++) {
            int e = 4 * (j * 256 + tid);
            int p = e >> 6, n4 = e & 63;
            *(ushort4*)&sHt[p * 72 + n4] = rHu[j];
        }
    }
    __syncthreads();
    if (c > 0) {
#pragma unroll
        for (int ks = 0; ks < 64; ks += 32) {
            bf16x8 bhh = *(const bf16x8*)&sHt[(pt + colL) * 72 + ks + kfrag];
#pragma unroll
            for (int tt = 0; tt < 3; tt++) {
                bf16x8 ac = *(const bf16x8*)&sCt[(tt * 16 + colL) * 72 + ks + kfrag];
                acc2[tt] = __builtin_amdgcn_mfma_f32_16x16x32_bf16(ac, bhh, acc2[tt], 0, 0, 0);
            }
        }
    }

    float dsk = Dskip[head];
#pragma unroll
    for (int tt = 0; tt < 3; tt++) {
#pragma unroll
        for (int r = 0; r < 4; r++) {
            int trow = tt * 16 + rbase + r;
            float y = fmaf(dsk, xo[tt][r], acc[tt][r]);
            if (c > 0) y = fmaf(sEx[trow], acc2[tt][r], y);
            xBCc[(size_t)(r0 + trow) * CDIM + head * HD + pt + colL] = y;
        }
    }
}

// gate v5: 4-row phase batching (6 barriers/block) + vectorized phase B (WopT).
__global__ __launch_bounds__(256) void k_gate(const float* __restrict__ chk,
        const float* __restrict__ Wf, const float* __restrict__ bf,
        const float* __restrict__ ysx, const float* __restrict__ norm_w,
        const float* __restrict__ WopT, const float* __restrict__ bop,
        float* __restrict__ feat) {
    int row0 = blockIdx.x * 8;
    int tid = threadIdx.x;
    __shared__ __align__(16) float sy[4][512];
    __shared__ float sred[4][256];
    __shared__ float swave[4][4];
    int c1 = tid, c2 = tid + 256;
    float wz1[16], wz2[16];
#pragma unroll
    for (int k = 0; k < 16; k++) {
        wz1[k] = Wf[k * DIP + c1];
        wz2[k] = Wf[k * DIP + c2];
    }
    float zb1 = bf[c1], zb2 = bf[c2];
    float nw1 = norm_w[c1], nw2 = norm_w[c2];
    int o = tid & 15, kg = tid >> 4;
    int wid = tid >> 6, lane = tid & 63;

    for (int g2 = 0; g2 < 2; g2++) {
        int rb = row0 + g2 * 4;
        float gn1[4], gn2[4];
#pragma unroll
        for (int r = 0; r < 4; r++) {
            int row = rb + r;
            const float4* cp = (const float4*)(chk + (size_t)row * 16);
            float4 cA = cp[0], cB = cp[1], cC = cp[2], cD = cp[3];
            float cv[16] = {cA.x,cA.y,cA.z,cA.w, cB.x,cB.y,cB.z,cB.w,
                            cC.x,cC.y,cC.z,cC.w, cD.x,cD.y,cD.z,cD.w};
            float z1 = zb1, z2 = zb2;
#pragma unroll
            for (int k = 0; k < 16; k++) {
                z1 = fmaf(cv[k], wz1[k], z1);
                z2 = fmaf(cv[k], wz2[k], z2);
            }
            float y1 = ysx[(size_t)row * CDIM + c1] * siluf(z1);
            float y2 = ysx[(size_t)row * CDIM + c2] * siluf(z2);
            gn1[r] = y1;
            gn2[r] = y2;
            float ss = y1 * y1 + y2 * y2;
#pragma unroll
            for (int off = 32; off >= 1; off >>= 1) ss += __shfl_xor(ss, off);
            if (lane == 0) swave[r][wid] = ss;
        }
        __syncthreads();
#pragma unroll
        for (int r = 0; r < 4; r++) {
            float tot = swave[r][0] + swave[r][1] + swave[r][2] + swave[r][3];
            float scale = 1.f / sqrtf(tot * (1.f / 512.f) + 1e-5f);
            sy[r][c1] = gn1[r] * scale * nw1;
            sy[r][c2] = gn2[r] * scale * nw2;
        }
        __syncthreads();
#pragma unroll
        for (int r = 0; r < 4; r++) {
            float ps = 0.f;
#pragma unroll
            for (int j4 = 0; j4 < 8; j4++) {
                int k = kg * 32 + j4 * 4;
                float4 syv = *(const float4*)&sy[r][k];
                float4 wv4 = *(const float4*)&WopT[o * 512 + k];
                ps = fmaf(syv.x, wv4.x, ps);
                ps = fmaf(syv.y, wv4.y, ps);
                ps = fmaf(syv.z, wv4.z, ps);
                ps = fmaf(syv.w, wv4.w, ps);
            }
            sred[r][kg * 16 + o] = ps;
        }
        __syncthreads();
        if (tid < 64) {
            int r = tid >> 4, oo = tid & 15;
            float s = bop[oo];
#pragma unroll
            for (int g = 0; g < 16; g++) s += sred[r][g * 16 + oo];
            int row = rb + r;
            int bb = row / LSEQ, t = row % LSEQ;
            feat[(size_t)(bb * NPG_C + t) * 16 + oo] = s;
        }
    }
}

// build per-dst adjacency
__global__ void k_scatter(const int* __restrict__ src, const int* __restrict__ dst,
                          int* __restrict__ cnt, int* __restrict__ slots) {
    int e = blockIdx.x * 256 + threadIdx.x;
    if (e >= N_EDGES_C) return;
    int d = dst[e];
    int pos = atomicAdd(&cnt[d], 1);
    if (pos < CAP) slots[(size_t)d * CAP + pos] = src[e];
}

// per-node message precompute: p[n] = relu(feat[n]@Wm + bm), bf16 output
__global__ __launch_bounds__(256) void k_proj(const float* __restrict__ feat,
        const float* __restrict__ Wm, const float* __restrict__ bm,
        unsigned short* __restrict__ p) {
    int tid = threadIdx.x;
    int c = tid & 127, half = tid >> 7;
    float w[16];
#pragma unroll
    for (int k = 0; k < 16; k++) w[k] = Wm[k * 128 + c];
    float bmv = bm[c];
    int base = blockIdx.x * 8;
#pragma unroll
    for (int q = 0; q < 4; q++) {
        int node = base + q * 2 + half;
        const float4* fr = (const float4*)(feat + (size_t)node * 16);
        float4 f0 = fr[0], f1 = fr[1], f2 = fr[2], f3 = fr[3];
        float m = bmv;
        m = fmaf(f0.x, w[0],  m); m = fmaf(f0.y, w[1],  m);
        m = fmaf(f0.z, w[2],  m); m = fmaf(f0.w, w[3],  m);
        m = fmaf(f1.x, w[4],  m); m = fmaf(f1.y, w[5],  m);
        m = fmaf(f1.z, w[6],  m); m = fmaf(f1.w, w[7],  m);
        m = fmaf(f2.x, w[8],  m); m = fmaf(f2.y, w[9],  m);
        m = fmaf(f2.z, w[10], m); m = fmaf(f2.w, w[11], m);
        m = fmaf(f3.x, w[12], m); m = fmaf(f3.y, w[13], m);
        m = fmaf(f3.z, w[14], m); m = fmaf(f3.w, w[15], m);
        p[(size_t)node * 128 + c] = f2bf(fmaxf(m, 0.f));
    }
}

// gather-sum aggregate: one wave per dst node; 4 edges in flight per wave.
__global__ __launch_bounds__(256) void k_agg2(const int* __restrict__ cnt,
        const int* __restrict__ slots, const unsigned short* __restrict__ p,
        float* __restrict__ agg) {
    int wid = threadIdx.x >> 6, lane = threadIdx.x & 63;
    int esub = lane >> 4, cl = lane & 15;
    int d = blockIdx.x * 4 + wid;
    int deg = cnt[d];
    if (deg > CAP) deg = CAP;
    const int* sl = slots + (size_t)d * CAP;

    float acc[8];
#pragma unroll
    for (int j = 0; j < 8; j++) acc[j] = 0.f;

    int e = esub;
    int s = (e < deg) ? sl[e] : -1;
    while (e < deg) {
        int scur = s;
        int en = e + 4;
        if (en < deg) s = sl[en];
        ushort4 v0, v1;
        {
            const unsigned short* pp = p + (size_t)scur * 128 + cl * 8;
            v0 = *(const ushort4*)(pp);
            v1 = *(const ushort4*)(pp + 4);
        }
        acc[0] += bf2f(v0.x); acc[1] += bf2f(v0.y);
        acc[2] += bf2f(v0.z); acc[3] += bf2f(v0.w);
        acc[4] += bf2f(v1.x); acc[5] += bf2f(v1.y);
        acc[6] += bf2f(v1.z); acc[7] += bf2f(v1.w);
        e = en;
    }
#pragma unroll
    for (int j = 0; j < 8; j++) {
        acc[j] += __shfl_xor(acc[j], 16);
        acc[j] += __shfl_xor(acc[j], 32);
    }
    if (esub == 0) {
        float4 o0 = { acc[0], acc[1], acc[2], acc[3] };
        float4 o1 = { acc[4], acc[5], acc[6], acc[7] };
        float* ap = agg + (size_t)d * 128 + cl * 8;
        *(float4*)(ap) = o0;
        *(float4*)(ap + 4) = o1;
    }
}

// node update MLP + output head, 32 nodes per block; 2ch x 8node thread tile.
#define UNB 32
__global__ __launch_bounds__(256) void k_upd2(const float* __restrict__ feat,
        const float* __restrict__ agg, const float* __restrict__ Wu,
        const float* __restrict__ bu, const float* __restrict__ Wo2,
        const float* __restrict__ bo2, float* __restrict__ out) {
    int g0 = blockIdx.x * UNB;
    int tid = threadIdx.x;
    __shared__ __align__(16) float sin_[UNB][144];
    __shared__ float part[4][8][2];
    for (int w = tid; w < UNB * 144; w += 256) {
        int node = w / 144, k = w - node * 144;
        sin_[node][k] = (k < 16) ? feat[(size_t)(g0 + node) * 16 + k]
                                 : agg[(size_t)(g0 + node) * 128 + (k - 16)];
    }
    __syncthreads();
    int c6 = tid & 63;
    int grp = tid >> 6;
    float acc[8][2];
#pragma unroll
    for (int nn = 0; nn < 8; nn++) { acc[nn][0] = 0.f; acc[nn][1] = 0.f; }

    for (int k0 = 0; k0 < 144; k0 += 4) {
        float wA0 = Wu[(k0 + 0) * 128 + c6], wB0 = Wu[(k0 + 0) * 128 + 64 + c6];
        float wA1 = Wu[(k0 + 1) * 128 + c6], wB1 = Wu[(k0 + 1) * 128 + 64 + c6];
        float wA2 = Wu[(k0 + 2) * 128 + c6], wB2 = Wu[(k0 + 2) * 128 + 64 + c6];
        float wA3 = Wu[(k0 + 3) * 128 + c6], wB3 = Wu[(k0 + 3) * 128 + 64 + c6];
#pragma unroll
        for (int nn = 0; nn < 8; nn++) {
            float4 s4 = *(const float4*)&sin_[grp * 8 + nn][k0];
            acc[nn][0] = fmaf(s4.x, wA0, acc[nn][0]);
            acc[nn][1] = fmaf(s4.x, wB0, acc[nn][1]);
            acc[nn][0] = fmaf(s4.y, wA1, acc[nn][0]);
            acc[nn][1] = fmaf(s4.y, wB1, acc[nn][1]);
            acc[nn][0] = fmaf(s4.z, wA2, acc[nn][0]);
            acc[nn][1] = fmaf(s4.z, wB2, acc[nn][1]);
            acc[nn][0] = fmaf(s4.w, wA3, acc[nn][0]);
            acc[nn][1] = fmaf(s4.w, wB3, acc[nn][1]);
        }
    }

    float buA = bu[c6], buB = bu[64 + c6];
    float2 woA = *(const float2*)&Wo2[c6 * 2];
    float2 woB = *(const float2*)&Wo2[(64 + c6) * 2];
    float p[8][2];
#pragma unroll
    for (int nn = 0; nn < 8; nn++) {
        float h0 = fmaxf(acc[nn][0] + buA, 0.f);
        float h1 = fmaxf(acc[nn][1] + buB, 0.f);
        p[nn][0] = h0 * woA.x + h1 * woB.x;
        p[nn][1] = h0 * woA.y + h1 * woB.y;
    }
#pragma unroll
    for (int off = 1; off < 64; off <<= 1) {
#pragma unroll
        for (int nn = 0; nn < 8; nn++) {
            p[nn][0] += __shfl_xor(p[nn][0], off);
            p[nn][1] += __shfl_xor(p[nn][1], off);
        }
    }
    if ((tid & 63) == 0) {
#pragma unroll
        for (int nn = 0; nn < 8; nn++) {
            part[grp][nn][0] = p[nn][0];
            part[grp][nn][1] = p[nn][1];
        }
    }
    __syncthreads();
    if (tid < 64) {
        int node = tid >> 1, o = tid & 1;
        out[(size_t)(g0 + node) * 2 + o] = part[node >> 3][node & 7][o] + bo2[o];
    }
}

extern "C" void kernel_launch(void* const* d_in, const int* in_sizes, int n_in,
                              void* d_out, int out_size, void* d_ws, size_t ws_size,
                              hipStream_t stream) {
    const float* node_inputs = (const float*)d_in[0];
    const int*   src_ids     = (const int*)d_in[1];
    const int*   dst_ids     = (const int*)d_in[2];
    const float* W_embed     = (const float*)d_in[3];
    const float* b_embed     = (const float*)d_in[4];
    const float* W_in        = (const float*)d_in[5];
    const float* b_in        = (const float*)d_in[6];
    const float* conv_w      = (const float*)d_in[7];
    const float* conv_b      = (const float*)d_in[8];
    const float* A_log       = (const float*)d_in[9];
    const float* dt_bias     = (const float*)d_in[10];
    const float* D_skip      = (const float*)d_in[11];
    const float* norm_w      = (const float*)d_in[12];
    const float* W_outp      = (const float*)d_in[13];
    const float* b_outp      = (const float*)d_in[14];
    const float* W_proj      = (const float*)d_in[15];
    const float* b_proj      = (const float*)d_in[16];
    const float* W_msg       = (const float*)d_in[17];
    const float* b_msg       = (const float*)d_in[18];
    const float* W_upd       = (const float*)d_in[19];
    const float* b_upd       = (const float*)d_in[20];
    const float* W_out       = (const float*)d_in[21];
    const float* b_out       = (const float*)d_in[22];

    float* ws   = (float*)d_ws;
    float* chk  = ws + OFF_CHK;
    float* Wf   = ws + OFF_WF;
    float* bf   = ws + OFF_BF;
    float* Wop  = ws + OFF_WOP;
    float* bop  = ws + OFF_BOP;
    float* xBCc = ws + OFF_XBC;
    float* dtv  = ws + OFF_DTV;
    float* ecum = ws + OFF_ECUM;
    unsigned short* hst = (unsigned short*)(ws + OFF_YS);
    unsigned short* bbf = (unsigned short*)(ws + OFF_BBF);
    float* WopT = ws + OFF_WOPT;
    float* feat = ws + OFF_FEAT;
    float* agg  = ws + OFF_AGG;
    float* Gm   = ws + OFF_AGG;
    unsigned short* pmsg = (unsigned short*)(ws + OFF_PROJ);
    int*   slots = (int*)(ws + OFF_XBC);
    int*   cnt   = (int*)(ws + OFF_DTV);
    float* out  = (float*)d_out;

    hipMemsetAsync(feat, 0, (size_t)N_NODES_C * 16 * 4, stream);

    k_gather<<<(NROWS * 16 + 255) / 256, 256, 0, stream>>>(node_inputs, chk);
    k_fusew<<<(16 * DIP + DIP + DIN * 16 + 16 + 16 * DIN + 255) / 256, 256, 0, stream>>>(
        W_embed, b_embed, W_in, b_in, W_outp, b_outp, W_proj, b_proj, Wf, bf, Wop, bop, WopT);
    k_conv<<<dim3(2, 8, BATCH_C), 320, 0, stream>>>(chk, Wf, bf, conv_w, conv_b, xBCc, bbf);
    k_dte<<<(BATCH_C * NCHK * NH) / 4, 256, 0, stream>>>(chk, Wf, bf, A_log, dt_bias, dtv, ecum);
    k_gmat<<<dim3(NCHK, BATCH_C), 256, 0, stream>>>(xBCc, Gm);
    k_scarry<<<dim3(NH, BATCH_C), 256, 0, stream>>>(xBCc, bbf, dtv, ecum, hst);
    k_intra<<<NCHK * NH * BATCH_C, 256, 0, stream>>>(xBCc, Gm, dtv, ecum, D_skip, hst);
    k_gate<<<NROWS / 8, 256, 0, stream>>>(chk, Wf, bf, xBCc, norm_w, WopT, bop, feat);
    hipMemsetAsync(cnt, 0, (size_t)N_NODES_C * 4, stream);
    k_scatter<<<(N_EDGES_C + 255) / 256, 256, 0, stream>>>(src_ids, dst_ids, cnt, slots);
    k_proj<<<N_NODES_C / 8, 256, 0, stream>>>(feat, W_msg, b_msg, pmsg);
    k_agg2<<<N_NODES_C / 4, 256, 0, stream>>>(cnt, slots, pmsg, agg);
    k_upd2<<<N_NODES_C / UNB, 256, 0, stream>>>(feat, agg, W_upd, b_upd, W_out, b_out, out);
}

// Round 24
// 374.384 us; speedup vs baseline: 1.0291x; 1.0291x over previous
//
#include <hip/hip_runtime.h>
#include <math.h>

#define LSEQ 624
#define NPG_C 1249
#define BATCH_C 64
#define NROWS (BATCH_C*LSEQ)          // 39936
#define N_NODES_C 79936
#define N_EDGES_C 639488
#define DIP 1160
#define DIN 512
#define CDIM 640
#define NH 8
#define HD 64
#define DS 64
#define CAP 96
#define TCH 48
#define NCHK 13
#define HSLOT 2097152                  // 64*8*4096 elements per h_start slot

// workspace layout (float offsets)
#define OFF_CHK   0
#define OFF_WF    638976
#define OFF_BF    657536
#define OFF_WOP   658944
#define OFF_BOP   667136
#define OFF_XBC   667392
#define OFF_DTV   26226432
#define OFF_EV    26545920
#define OFF_YS    26865408
#define OFF_FEAT  47312640
#define OFF_AGG   48591616
#define OFF_ECUM  (OFF_AGG + 2000000)
#define OFF_BBF   (OFF_AGG + 2400000)  // bf16 B mirror
#define OFF_PROJ  (OFF_XBC + 8000000)  // bf16 pmsg

typedef __attribute__((ext_vector_type(8))) short bf16x8;
typedef __attribute__((ext_vector_type(4))) float f32x4;

__device__ __forceinline__ float siluf(float x) {
    return x / (1.f + __expf(-x));
}

__device__ __forceinline__ unsigned short f2bf(float f) {
    unsigned int u = __float_as_uint(f);
    u += 0x7fffu + ((u >> 16) & 1u);
    return (unsigned short)(u >> 16);
}
__device__ __forceinline__ float bf2f(unsigned short h) {
    return __uint_as_float(((unsigned int)h) << 16);
}

// hst layout: bf16, [p][n]
__device__ __forceinline__ unsigned short* hstp(unsigned short* hst, int c, int b, int head) {
    return hst + (size_t)(c - 1) * HSLOT + (size_t)(b * NH + head) * 4096;
}

// gather check-node rows
__global__ void k_gather(const float* __restrict__ ni, float* __restrict__ chk) {
    int gid = blockIdx.x * 256 + threadIdx.x;
    if (gid >= NROWS * 16) return;
    int row = gid >> 4, k = gid & 15;
    int node = (row / LSEQ) * NPG_C + (row % LSEQ);
    chk[gid] = ni[node * 16 + k];
}

// fused weights
__global__ void k_fusew(const float* __restrict__ We, const float* __restrict__ be,
                        const float* __restrict__ Wi, const float* __restrict__ bi,
                        const float* __restrict__ Wo, const float* __restrict__ bo,
                        const float* __restrict__ Wp, const float* __restrict__ bp,
                        float* __restrict__ Wf, float* __restrict__ bf,
                        float* __restrict__ Wop, float* __restrict__ bop) {
    int id = blockIdx.x * 256 + threadIdx.x;
    if (id < 16 * DIP) {
        int i = id / DIP, j = id % DIP;
        float s = 0.f;
        for (int k = 0; k < 256; k++) s = fmaf(We[i * 256 + k], Wi[k * DIP + j], s);
        Wf[id] = s;
    } else if (id < 16 * DIP + DIP) {
        int j = id - 16 * DIP;
        float s = bi[j];
        for (int k = 0; k < 256; k++) s = fmaf(be[k], Wi[k * DIP + j], s);
        bf[j] = s;
    } else if (id < 16 * DIP + DIP + DIN * 16) {
        int id2 = id - (16 * DIP + DIP);
        int c = id2 >> 4, o = id2 & 15;
        float s = 0.f;
        for (int k = 0; k < 256; k++) s = fmaf(Wo[c * 256 + k], Wp[k * 16 + o], s);
        Wop[id2] = s;
    } else if (id < 16 * DIP + DIP + DIN * 16 + 16) {
        int o = id - (16 * DIP + DIP + DIN * 16);
        float s = bp[o];
        for (int k = 0; k < 256; k++) s = fmaf(bo[k], Wp[k * 16 + o], s);
        bop[o] = s;
    }
}

// fused in_proj(xBC cols) + causal depthwise conv + silu; emits bf16 B mirror
__global__ __launch_bounds__(320) void k_conv(const float* __restrict__ chk,
        const float* __restrict__ Wf, const float* __restrict__ bf,
        const float* __restrict__ cw, const float* __restrict__ cb,
        float* __restrict__ xBCc, unsigned short* __restrict__ bbf) {
    int c = blockIdx.x * 320 + threadIdx.x;
    int t0 = blockIdx.y * 78;
    int b = blockIdx.z;
    float w[16];
#pragma unroll
    for (int k = 0; k < 16; k++) w[k] = Wf[k * DIP + DIN + c];
    float bfx = bf[DIN + c];
    float k0 = cw[c * 4 + 0], k1 = cw[c * 4 + 1], k2 = cw[c * 4 + 2], k3 = cw[c * 4 + 3];
    float cbv = cb[c];
    const float* crow = chk + (size_t)(b * LSEQ) * 16;
    float* out = xBCc + (size_t)(b * LSEQ) * CDIM + c;
    int isB = (c >= 512 && c < 576);
    unsigned short* bout = bbf + (size_t)(b * LSEQ) * 64 + (c - 512);

    float w0 = 0.f, w1 = 0.f, w2 = 0.f;
#pragma unroll
    for (int d = 3; d >= 1; d--) {
        int tau = t0 - d;
        float s = 0.f;
        if (tau >= 0) {
            s = bfx;
            const float* cr = crow + tau * 16;
#pragma unroll
            for (int k = 0; k < 16; k++) s = fmaf(cr[k], w[k], s);
        }
        if (d == 3) w0 = s; else if (d == 2) w1 = s; else w2 = s;
    }
    for (int t = t0; t < t0 + 78; t++) {
        const float* cr = crow + t * 16;
        float w3 = bfx;
#pragma unroll
        for (int k = 0; k < 16; k++) w3 = fmaf(cr[k], w[k], w3);
        float a = fmaf(k0, w0, fmaf(k1, w1, fmaf(k2, w2, fmaf(k3, w3, cbv))));
        float v = siluf(a);
        out[(size_t)t * CDIM] = v;
        if (isB) bout[(size_t)t * 64] = f2bf(v);
        w0 = w1; w1 = w2; w2 = w3;
    }
}

// fused dt + within-chunk prefix
__global__ __launch_bounds__(256) void k_dte(const float* __restrict__ chk,
        const float* __restrict__ Wf, const float* __restrict__ bf,
        const float* __restrict__ A_log, const float* __restrict__ dt_bias,
        float* __restrict__ dtv, float* __restrict__ ecum) {
    int s = blockIdx.x * 4 + (threadIdx.x >> 6);
    int lane = threadIdx.x & 63;
    int h = s & 7;
    int cb = s >> 3;
    int c = cb % NCHK, b = cb / NCHK;
    int r0 = b * LSEQ + c * TCH;
    float wcol[16];
#pragma unroll
    for (int k = 0; k < 16; k++) wcol[k] = Wf[k * DIP + DIN + CDIM + h];
    float base = bf[DIN + CDIM + h] + dt_bias[h];
    float nA = -__expf(A_log[h]);
    float v = 0.f, sp = 0.f;
    if (lane < TCH) {
        const float* cr = chk + (size_t)(r0 + lane) * 16;
        float acc = base;
#pragma unroll
        for (int k = 0; k < 16; k++) acc = fmaf(cr[k], wcol[k], acc);
        sp = (acc > 20.f) ? acc : log1pf(__expf(acc));
        v = nA * sp;
    }
#pragma unroll
    for (int off = 1; off < 64; off <<= 1) {
        float u = __shfl_up(v, off);
        if (lane >= off) v += u;
    }
    if (lane < TCH) {
        dtv[(size_t)(r0 + lane) * NH + h] = sp;
        ecum[(size_t)(r0 + lane) * NH + h] = v;
    }
}

// MFMA state carry: grid (8,64); wave wv owns p-tile; acc = h state.
__global__ __launch_bounds__(256) void k_scarry(const float* __restrict__ xBCc,
        const unsigned short* __restrict__ bbf,
        const float* __restrict__ dtv, const float* __restrict__ ecum,
        unsigned short* __restrict__ hst) {
    int head = blockIdx.x, b = blockIdx.y;
    int tid = threadIdx.x;
    int lane = tid & 63, wv = tid >> 6;
    int bs = b * LSEQ;
    __shared__ unsigned short sXh[64 * 72];
    __shared__ unsigned short sXl[64 * 72];
    __shared__ unsigned short sBn[64 * 72];

    int colL = lane & 15;
    int rbase = (lane >> 4) * 4;
    int kfrag = 8 * (lane >> 4);

    f32x4 acc[4] = { {0,0,0,0}, {0,0,0,0}, {0,0,0,0}, {0,0,0,0} };

    float4 rX[3];
    ushort4 rBu[3];
    float rEc[3], rDt[3], rEcL = 0.f;

#define SC_ISSUE(cc)                                                                \
    {                                                                               \
        int r0i = bs + (cc) * TCH;                                                  \
        _Pragma("unroll")                                                           \
        for (int jj = 0; jj < 3; jj++) {                                            \
            int g = jj * 256 + tid; int t = g >> 4; int col = (g & 15) * 4;         \
            rX[jj] = *(const float4*)(xBCc + (size_t)(r0i + t) * CDIM + head * HD + col); \
            rBu[jj] = *(const ushort4*)(bbf + (size_t)(r0i + t) * 64 + col);        \
            rEc[jj] = ecum[(size_t)(r0i + t) * NH + head];                          \
            rDt[jj] = dtv[(size_t)(r0i + t) * NH + head];                           \
        }                                                                           \
        rEcL = ecum[(size_t)(r0i + TCH - 1) * NH + head];                           \
    }

    {
        int p = tid >> 2, k4 = 48 + (tid & 3) * 4;
        ushort4 z = { 0, 0, 0, 0 };
        *(ushort4*)&sXh[p * 72 + k4] = z;
        *(ushort4*)&sXl[p * 72 + k4] = z;
        *(ushort4*)&sBn[p * 72 + k4] = z;
    }

    SC_ISSUE(0);
    for (int c = 0; c < NCHK; c++) {
        __syncthreads();
        float eL = __expf(rEcL);
#pragma unroll
        for (int jj = 0; jj < 3; jj++) {
            int g = jj * 256 + tid;
            int t = g >> 4, col = (g & 15) * 4;
            float w = __expf(rEcL - rEc[jj]) * rDt[jj];
            float m0 = w * rX[jj].x, m1 = w * rX[jj].y;
            float m2 = w * rX[jj].z, m3 = w * rX[jj].w;
            unsigned short h0 = f2bf(m0), h1 = f2bf(m1), h2 = f2bf(m2), h3 = f2bf(m3);
            sXh[(col + 0) * 72 + t] = h0;
            sXh[(col + 1) * 72 + t] = h1;
            sXh[(col + 2) * 72 + t] = h2;
            sXh[(col + 3) * 72 + t] = h3;
            sXl[(col + 0) * 72 + t] = f2bf(m0 - bf2f(h0));
            sXl[(col + 1) * 72 + t] = f2bf(m1 - bf2f(h1));
            sXl[(col + 2) * 72 + t] = f2bf(m2 - bf2f(h2));
            sXl[(col + 3) * 72 + t] = f2bf(m3 - bf2f(h3));
            sBn[(col + 0) * 72 + t] = rBu[jj].x;
            sBn[(col + 1) * 72 + t] = rBu[jj].y;
            sBn[(col + 2) * 72 + t] = rBu[jj].z;
            sBn[(col + 3) * 72 + t] = rBu[jj].w;
        }
        __syncthreads();
        if (c + 1 < NCHK) SC_ISSUE(c + 1);

        if (c > 0) {
            unsigned short* hp = hstp(hst, c, b, head);
#pragma unroll
            for (int nt = 0; nt < 4; nt++)
#pragma unroll
                for (int r = 0; r < 4; r++)
                    hp[(wv * 16 + rbase + r) * 64 + nt * 16 + colL] = f2bf(acc[nt][r]);
        }
#pragma unroll
        for (int nt = 0; nt < 4; nt++)
#pragma unroll
            for (int r = 0; r < 4; r++)
                acc[nt][r] *= eL;
#pragma unroll
        for (int ks = 0; ks < 64; ks += 32) {
            bf16x8 ah = *(const bf16x8*)&sXh[(wv * 16 + colL) * 72 + ks + kfrag];
            bf16x8 al = *(const bf16x8*)&sXl[(wv * 16 + colL) * 72 + ks + kfrag];
#pragma unroll
            for (int nt = 0; nt < 4; nt++) {
                bf16x8 bb = *(const bf16x8*)&sBn[(nt * 16 + colL) * 72 + ks + kfrag];
                acc[nt] = __builtin_amdgcn_mfma_f32_16x16x32_bf16(ah, bb, acc[nt], 0, 0, 0);
                acc[nt] = __builtin_amdgcn_mfma_f32_16x16x32_bf16(al, bb, acc[nt], 0, 0, 0);
            }
        }
    }
#undef SC_ISSUE
}

// intra-chunk v2: fused G = C.B^T (MFMA) + M build + Y1 = M@X + Y2 = C@H.
// Phase-overlaid LDS (38.2 KB -> 4 blocks/CU):
//  R1 @0      (13824): phase A = Ct[48][72] + Bs[48][72];  later sXf[48][64] f32
//  R2 @13824  ( 9984): sG[48][52] f32;                     later sXh/sHt[64][72]
//  R3 @23808  (13824): sMh[48][72] + sMl[48][72];          phase2 sCt overlays sMl
__global__ __launch_bounds__(256) void k_intra(float* __restrict__ xBCc,
        const unsigned short* __restrict__ bbf,
        const float* __restrict__ dtv, const float* __restrict__ ecum,
        const float* __restrict__ Dskip, const unsigned short* __restrict__ hst) {
    int bid = blockIdx.x;
    int xcd = bid & 7;
    int head = (bid >> 3) & 7;
    int g = (bid >> 6) * 8 + xcd;
    int c = g % NCHK, b = g / NCHK;
    int tid = threadIdx.x;
    int lane = tid & 63;
    int wv = tid >> 6;
    int bs = b * LSEQ;
    int r0 = bs + c * TCH;

    __shared__ __align__(16) unsigned char smraw[38208];
    unsigned short* sCt2 = (unsigned short*)(smraw);
    unsigned short* sBs  = (unsigned short*)(smraw + 6912);
    float* sXf = (float*)(smraw);
    float* sG  = (float*)(smraw + 13824);
    unsigned short* sXh = (unsigned short*)(smraw + 13824);
    unsigned short* sHt = (unsigned short*)(smraw + 13824);
    unsigned short* sMh = (unsigned short*)(smraw + 23808);
    unsigned short* sMl = (unsigned short*)(smraw + 30720);
    unsigned short* sCt = (unsigned short*)(smraw + 30720);
    float* sE  = (float*)(smraw + 37632);
    float* sEx = (float*)(smraw + 37824);
    float* sdt = (float*)(smraw + 38016);

    int colL = lane & 15;
    int rbase = (lane >> 4) * 4;
    int kfrag = 8 * (lane >> 4);
    int pt = wv * 16;

    ushort4 rHu[4];
    if (c > 0) {
        const unsigned short* hp = hstp((unsigned short*)hst, c, b, head);
#pragma unroll
        for (int j = 0; j < 4; j++)
            rHu[j] = *(const ushort4*)(hp + 4 * (j * 256 + tid));
    }

    float4 rXv[3];
    ushort4 rCu[3];
#pragma unroll
    for (int j = 0; j < 3; j++) {
        int g2 = j * 256 + tid;
        int t = g2 >> 4, col = (g2 & 15) * 4;
        const float* rowp = xBCc + (size_t)(r0 + t) * CDIM;
        rXv[j] = *(const float4*)(rowp + head * HD + col);
        float4 cv = *(const float4*)(rowp + 576 + col);
        ushort4 cu = { f2bf(cv.x), f2bf(cv.y), f2bf(cv.z), f2bf(cv.w) };
        rCu[j] = cu;
        ushort4 bu = *(const ushort4*)(bbf + (size_t)(r0 + t) * 64 + col);
        *(ushort4*)&sCt2[t * 72 + col] = cu;
        *(ushort4*)&sBs[t * 72 + col] = bu;
    }
    if (tid < TCH) {
        float e = ecum[(size_t)(r0 + tid) * NH + head];
        sE[tid] = e;
        sEx[tid] = __expf(e);
        sdt[tid] = dtv[(size_t)(r0 + tid) * NH + head];
    }
    __syncthreads();

    // G = C . B^T via MFMA; tile idx = tt*3+ss in {wv, wv+4, wv+8}
#pragma unroll
    for (int slot = 0; slot < 3; slot++) {
        int idx = wv + slot * 4;
        if (idx < 9) {
            int tt = idx / 3, ss = idx - tt * 3;
            f32x4 a = { 0.f, 0.f, 0.f, 0.f };
#pragma unroll
            for (int ks = 0; ks < 64; ks += 32) {
                bf16x8 ca = *(const bf16x8*)&sCt2[(tt * 16 + colL) * 72 + ks + kfrag];
                bf16x8 bb = *(const bf16x8*)&sBs[(ss * 16 + colL) * 72 + ks + kfrag];
                a = __builtin_amdgcn_mfma_f32_16x16x32_bf16(ca, bb, a, 0, 0, 0);
            }
#pragma unroll
            for (int r = 0; r < 4; r++)
                sG[(tt * 16 + rbase + r) * 52 + ss * 16 + colL] = a[r];
        }
    }
    __syncthreads();

    // stage X (overwrites C/B region) + build M hi/lo from sG
#pragma unroll
    for (int j = 0; j < 3; j++) {
        int g2 = j * 256 + tid;
        int t = g2 >> 4, col = (g2 & 15) * 4;
        *(float4*)&sXf[t * 64 + col] = rXv[j];
    }
#pragma unroll
    for (int k = 0; k < 9; k++) {
        int id = k * 256 + tid;
        int t = id / TCH, s = id - t * TCH;
        float gv = sG[t * 52 + s];
        float m = (s <= t) ? __expf(sE[t] - sE[s]) * sdt[s] * gv : 0.f;
        unsigned short mh = f2bf(m);
        sMh[t * 72 + s] = mh;
        sMl[t * 72 + s] = f2bf(m - bf2f(mh));
    }
    for (int w = tid; w < 768; w += 256) {
        int t = w >> 4, s = 48 + (w & 15);
        sMh[t * 72 + s] = 0;
        sMl[t * 72 + s] = 0;
    }
    __syncthreads();

    // transpose X -> sXh (overwrites sG) + xo capture
#pragma unroll
    for (int i = 0; i < 3; i++) {
        int w = i * 256 + tid;
        int p = w & 63, k4 = (w >> 6) * 4;
        float v0 = sXf[(k4 + 0) * 64 + p];
        float v1 = sXf[(k4 + 1) * 64 + p];
        float v2 = sXf[(k4 + 2) * 64 + p];
        float v3 = sXf[(k4 + 3) * 64 + p];
        ushort4 hi = { f2bf(v0), f2bf(v1), f2bf(v2), f2bf(v3) };
        *(ushort4*)&sXh[p * 72 + k4] = hi;
    }
    {
        int p = tid >> 2, k4 = 48 + (tid & 3) * 4;
        ushort4 z = { 0, 0, 0, 0 };
        *(ushort4*)&sXh[p * 72 + k4] = z;
    }
    float xo[3][4];
#pragma unroll
    for (int tt = 0; tt < 3; tt++)
#pragma unroll
        for (int r = 0; r < 4; r++)
            xo[tt][r] = sXf[(tt * 16 + rbase + r) * 64 + pt + colL];
    __syncthreads();

    // phase 1: Y1 = M @ X
    f32x4 acc[3] = { {0,0,0,0}, {0,0,0,0}, {0,0,0,0} };
    f32x4 acc2[3] = { {0,0,0,0}, {0,0,0,0}, {0,0,0,0} };
#pragma unroll
    for (int ks = 0; ks < 64; ks += 32) {
        bf16x8 bh = *(const bf16x8*)&sXh[(pt + colL) * 72 + ks + kfrag];
#pragma unroll
        for (int tt = 0; tt < 3; tt++) {
            bf16x8 ah = *(const bf16x8*)&sMh[(tt * 16 + colL) * 72 + ks + kfrag];
            bf16x8 al = *(const bf16x8*)&sMl[(tt * 16 + colL) * 72 + ks + kfrag];
            acc[tt] = __builtin_amdgcn_mfma_f32_16x16x32_bf16(ah, bh, acc[tt], 0, 0, 0);
            acc[tt] = __builtin_amdgcn_mfma_f32_16x16x32_bf16(al, bh, acc[tt], 0, 0, 0);
        }
    }
    __syncthreads();
    // overlay phase-2 operands
#pragma unroll
    for (int j = 0; j < 3; j++) {
        int g2 = j * 256 + tid;
        int t = g2 >> 4, col = (g2 & 15) * 4;
        *(ushort4*)&sCt[t * 72 + col] = rCu[j];
    }
    if (c > 0) {
#pragma unroll
        for (int j = 0; j < 4; j++) {
            int e = 4 * (j * 256 + tid);
            int p = e >> 6, n4 = e & 63;
            *(ushort4*)&sHt[p * 72 + n4] = rHu[j];
        }
    }
    __syncthreads();
    if (c > 0) {
#pragma unroll
        for (int ks = 0; ks < 64; ks += 32) {
            bf16x8 bhh = *(const bf16x8*)&sHt[(pt + colL) * 72 + ks + kfrag];
#pragma unroll
            for (int tt = 0; tt < 3; tt++) {
                bf16x8 ac = *(const bf16x8*)&sCt[(tt * 16 + colL) * 72 + ks + kfrag];
                acc2[tt] = __builtin_amdgcn_mfma_f32_16x16x32_bf16(ac, bhh, acc2[tt], 0, 0, 0);
            }
        }
    }

    float dsk = Dskip[head];
#pragma unroll
    for (int tt = 0; tt < 3; tt++) {
#pragma unroll
        for (int r = 0; r < 4; r++) {
            int trow = tt * 16 + rbase + r;
            float y = fmaf(dsk, xo[tt][r], acc[tt][r]);
            if (c > 0) y = fmaf(sEx[trow], acc2[tt][r], y);
            xBCc[(size_t)(r0 + trow) * CDIM + head * HD + pt + colL] = y;
        }
    }
}

// gate v4 (proven 61 us): r17 structure, phases batched across 2 rows.
__global__ __launch_bounds__(256) void k_gate(const float* __restrict__ chk,
        const float* __restrict__ Wf, const float* __restrict__ bf,
        const float* __restrict__ ysx, const float* __restrict__ norm_w,
        const float* __restrict__ Wop, const float* __restrict__ bop,
        float* __restrict__ feat) {
    int row0 = blockIdx.x * 8;
    int tid = threadIdx.x;
    __shared__ float sy[2][512];
    __shared__ float sred[2][256];
    __shared__ float swave[2][4];
    int c1 = tid, c2 = tid + 256;
    float wz1[16], wz2[16];
#pragma unroll
    for (int k = 0; k < 16; k++) {
        wz1[k] = Wf[k * DIP + c1];
        wz2[k] = Wf[k * DIP + c2];
    }
    float zb1 = bf[c1], zb2 = bf[c2];
    float nw1 = norm_w[c1], nw2 = norm_w[c2];
    int o = tid & 15, kg = tid >> 4;
    int wid = tid >> 6, lane = tid & 63;

    for (int g2 = 0; g2 < 4; g2++) {
        int rb = row0 + g2 * 2;
        float gn1[2], gn2[2];
#pragma unroll
        for (int r = 0; r < 2; r++) {
            int row = rb + r;
            const float4* cp = (const float4*)(chk + (size_t)row * 16);
            float4 cA = cp[0], cB = cp[1], cC = cp[2], cD = cp[3];
            float cv[16] = {cA.x,cA.y,cA.z,cA.w, cB.x,cB.y,cB.z,cB.w,
                            cC.x,cC.y,cC.z,cC.w, cD.x,cD.y,cD.z,cD.w};
            float z1 = zb1, z2 = zb2;
#pragma unroll
            for (int k = 0; k < 16; k++) {
                z1 = fmaf(cv[k], wz1[k], z1);
                z2 = fmaf(cv[k], wz2[k], z2);
            }
            float y1 = ysx[(size_t)row * CDIM + c1] * siluf(z1);
            float y2 = ysx[(size_t)row * CDIM + c2] * siluf(z2);
            gn1[r] = y1;
            gn2[r] = y2;
            float ss = y1 * y1 + y2 * y2;
#pragma unroll
            for (int off = 32; off >= 1; off >>= 1) ss += __shfl_xor(ss, off);
            if (lane == 0) swave[r][wid] = ss;
        }
        __syncthreads();
#pragma unroll
        for (int r = 0; r < 2; r++) {
            float tot = swave[r][0] + swave[r][1] + swave[r][2] + swave[r][3];
            float scale = 1.f / sqrtf(tot * (1.f / 512.f) + 1e-5f);
            sy[r][c1] = gn1[r] * scale * nw1;
            sy[r][c2] = gn2[r] * scale * nw2;
        }
        __syncthreads();
#pragma unroll
        for (int r = 0; r < 2; r++) {
            float ps = 0.f;
#pragma unroll
            for (int j = 0; j < 32; j++) {
                int k = kg * 32 + j;
                ps = fmaf(sy[r][k], Wop[k * 16 + o], ps);
            }
            sred[r][kg * 16 + o] = ps;
        }
        __syncthreads();
        if (tid < 32) {
            int r = tid >> 4, oo = tid & 15;
            float s = bop[oo];
#pragma unroll
            for (int g = 0; g < 16; g++) s += sred[r][g * 16 + oo];
            int row = rb + r;
            int bb = row / LSEQ, t = row % LSEQ;
            feat[(size_t)(bb * NPG_C + t) * 16 + oo] = s;
        }
    }
}

// build per-dst adjacency
__global__ void k_scatter(const int* __restrict__ src, const int* __restrict__ dst,
                          int* __restrict__ cnt, int* __restrict__ slots) {
    int e = blockIdx.x * 256 + threadIdx.x;
    if (e >= N_EDGES_C) return;
    int d = dst[e];
    int pos = atomicAdd(&cnt[d], 1);
    if (pos < CAP) slots[(size_t)d * CAP + pos] = src[e];
}

// per-node message precompute: p[n] = relu(feat[n]@Wm + bm), bf16 output
__global__ __launch_bounds__(256) void k_proj(const float* __restrict__ feat,
        const float* __restrict__ Wm, const float* __restrict__ bm,
        unsigned short* __restrict__ p) {
    int tid = threadIdx.x;
    int c = tid & 127, half = tid >> 7;
    float w[16];
#pragma unroll
    for (int k = 0; k < 16; k++) w[k] = Wm[k * 128 + c];
    float bmv = bm[c];
    int base = blockIdx.x * 8;
#pragma unroll
    for (int q = 0; q < 4; q++) {
        int node = base + q * 2 + half;
        const float4* fr = (const float4*)(feat + (size_t)node * 16);
        float4 f0 = fr[0], f1 = fr[1], f2 = fr[2], f3 = fr[3];
        float m = bmv;
        m = fmaf(f0.x, w[0],  m); m = fmaf(f0.y, w[1],  m);
        m = fmaf(f0.z, w[2],  m); m = fmaf(f0.w, w[3],  m);
        m = fmaf(f1.x, w[4],  m); m = fmaf(f1.y, w[5],  m);
        m = fmaf(f1.z, w[6],  m); m = fmaf(f1.w, w[7],  m);
        m = fmaf(f2.x, w[8],  m); m = fmaf(f2.y, w[9],  m);
        m = fmaf(f2.z, w[10], m); m = fmaf(f2.w, w[11], m);
        m = fmaf(f3.x, w[12], m); m = fmaf(f3.y, w[13], m);
        m = fmaf(f3.z, w[14], m); m = fmaf(f3.w, w[15], m);
        p[(size_t)node * 128 + c] = f2bf(fmaxf(m, 0.f));
    }
}

// gather-sum aggregate: one wave per dst node; 4 edges in flight per wave.
__global__ __launch_bounds__(256) void k_agg2(const int* __restrict__ cnt,
        const int* __restrict__ slots, const unsigned short* __restrict__ p,
        float* __restrict__ agg) {
    int wid = threadIdx.x >> 6, lane = threadIdx.x & 63;
    int esub = lane >> 4, cl = lane & 15;
    int d = blockIdx.x * 4 + wid;
    int deg = cnt[d];
    if (deg > CAP) deg = CAP;
    const int* sl = slots + (size_t)d * CAP;

    float acc[8];
#pragma unroll
    for (int j = 0; j < 8; j++) acc[j] = 0.f;

    int e = esub;
    int s = (e < deg) ? sl[e] : -1;
    while (e < deg) {
        int scur = s;
        int en = e + 4;
        if (en < deg) s = sl[en];
        ushort4 v0, v1;
        {
            const unsigned short* pp = p + (size_t)scur * 128 + cl * 8;
            v0 = *(const ushort4*)(pp);
            v1 = *(const ushort4*)(pp + 4);
        }
        acc[0] += bf2f(v0.x); acc[1] += bf2f(v0.y);
        acc[2] += bf2f(v0.z); acc[3] += bf2f(v0.w);
        acc[4] += bf2f(v1.x); acc[5] += bf2f(v1.y);
        acc[6] += bf2f(v1.z); acc[7] += bf2f(v1.w);
        e = en;
    }
#pragma unroll
    for (int j = 0; j < 8; j++) {
        acc[j] += __shfl_xor(acc[j], 16);
        acc[j] += __shfl_xor(acc[j], 32);
    }
    if (esub == 0) {
        float4 o0 = { acc[0], acc[1], acc[2], acc[3] };
        float4 o1 = { acc[4], acc[5], acc[6], acc[7] };
        float* ap = agg + (size_t)d * 128 + cl * 8;
        *(float4*)(ap) = o0;
        *(float4*)(ap + 4) = o1;
    }
}

// node update MLP + output head, 32 nodes per block; 2ch x 8node thread tile.
#define UNB 32
__global__ __launch_bounds__(256) void k_upd2(const float* __restrict__ feat,
        const float* __restrict__ agg, const float* __restrict__ Wu,
        const float* __restrict__ bu, const float* __restrict__ Wo2,
        const float* __restrict__ bo2, float* __restrict__ out) {
    int g0 = blockIdx.x * UNB;
    int tid = threadIdx.x;
    __shared__ __align__(16) float sin_[UNB][144];
    __shared__ float part[4][8][2];
    for (int w = tid; w < UNB * 144; w += 256) {
        int node = w / 144, k = w - node * 144;
        sin_[node][k] = (k < 16) ? feat[(size_t)(g0 + node) * 16 + k]
                                 : agg[(size_t)(g0 + node) * 128 + (k - 16)];
    }
    __syncthreads();
    int c6 = tid & 63;
    int grp = tid >> 6;
    float acc[8][2];
#pragma unroll
    for (int nn = 0; nn < 8; nn++) { acc[nn][0] = 0.f; acc[nn][1] = 0.f; }

    for (int k0 = 0; k0 < 144; k0 += 4) {
        float wA0 = Wu[(k0 + 0) * 128 + c6], wB0 = Wu[(k0 + 0) * 128 + 64 + c6];
        float wA1 = Wu[(k0 + 1) * 128 + c6], wB1 = Wu[(k0 + 1) * 128 + 64 + c6];
        float wA2 = Wu[(k0 + 2) * 128 + c6], wB2 = Wu[(k0 + 2) * 128 + 64 + c6];
        float wA3 = Wu[(k0 + 3) * 128 + c6], wB3 = Wu[(k0 + 3) * 128 + 64 + c6];
#pragma unroll
        for (int nn = 0; nn < 8; nn++) {
            float4 s4 = *(const float4*)&sin_[grp * 8 + nn][k0];
            acc[nn][0] = fmaf(s4.x, wA0, acc[nn][0]);
            acc[nn][1] = fmaf(s4.x, wB0, acc[nn][1]);
            acc[nn][0] = fmaf(s4.y, wA1, acc[nn][0]);
            acc[nn][1] = fmaf(s4.y, wB1, acc[nn][1]);
            acc[nn][0] = fmaf(s4.z, wA2, acc[nn][0]);
            acc[nn][1] = fmaf(s4.z, wB2, acc[nn][1]);
            acc[nn][0] = fmaf(s4.w, wA3, acc[nn][0]);
            acc[nn][1] = fmaf(s4.w, wB3, acc[nn][1]);
        }
    }

    float buA = bu[c6], buB = bu[64 + c6];
    float2 woA = *(const float2*)&Wo2[c6 * 2];
    float2 woB = *(const float2*)&Wo2[(64 + c6) * 2];
    float p[8][2];
#pragma unroll
    for (int nn = 0; nn < 8; nn++) {
        float h0 = fmaxf(acc[nn][0] + buA, 0.f);
        float h1 = fmaxf(acc[nn][1] + buB, 0.f);
        p[nn][0] = h0 * woA.x + h1 * woB.x;
        p[nn][1] = h0 * woA.y + h1 * woB.y;
    }
#pragma unroll
    for (int off = 1; off < 64; off <<= 1) {
#pragma unroll
        for (int nn = 0; nn < 8; nn++) {
            p[nn][0] += __shfl_xor(p[nn][0], off);
            p[nn][1] += __shfl_xor(p[nn][1], off);
        }
    }
    if ((tid & 63) == 0) {
#pragma unroll
        for (int nn = 0; nn < 8; nn++) {
            part[grp][nn][0] = p[nn][0];
            part[grp][nn][1] = p[nn][1];
        }
    }
    __syncthreads();
    if (tid < 64) {
        int node = tid >> 1, o = tid & 1;
        out[(size_t)(g0 + node) * 2 + o] = part[node >> 3][node & 7][o] + bo2[o];
    }
}

extern "C" void kernel_launch(void* const* d_in, const int* in_sizes, int n_in,
                              void* d_out, int out_size, void* d_ws, size_t ws_size,
                              hipStream_t stream) {
    const float* node_inputs = (const float*)d_in[0];
    const int*   src_ids     = (const int*)d_in[1];
    const int*   dst_ids     = (const int*)d_in[2];
    const float* W_embed     = (const float*)d_in[3];
    const float* b_embed     = (const float*)d_in[4];
    const float* W_in        = (const float*)d_in[5];
    const float* b_in        = (const float*)d_in[6];
    const float* conv_w      = (const float*)d_in[7];
    const float* conv_b      = (const float*)d_in[8];
    const float* A_log       = (const float*)d_in[9];
    const float* dt_bias     = (const float*)d_in[10];
    const float* D_skip      = (const float*)d_in[11];
    const float* norm_w      = (const float*)d_in[12];
    const float* W_outp      = (const float*)d_in[13];
    const float* b_outp      = (const float*)d_in[14];
    const float* W_proj      = (const float*)d_in[15];
    const float* b_proj      = (const float*)d_in[16];
    const float* W_msg       = (const float*)d_in[17];
    const float* b_msg       = (const float*)d_in[18];
    const float* W_upd       = (const float*)d_in[19];
    const float* b_upd       = (const float*)d_in[20];
    const float* W_out       = (const float*)d_in[21];
    const float* b_out       = (const float*)d_in[22];

    float* ws   = (float*)d_ws;
    float* chk  = ws + OFF_CHK;
    float* Wf   = ws + OFF_WF;
    float* bf   = ws + OFF_BF;
    float* Wop  = ws + OFF_WOP;
    float* bop  = ws + OFF_BOP;
    float* xBCc = ws + OFF_XBC;
    float* dtv  = ws + OFF_DTV;
    float* ecum = ws + OFF_ECUM;
    unsigned short* hst = (unsigned short*)(ws + OFF_YS);
    unsigned short* bbf = (unsigned short*)(ws + OFF_BBF);
    float* feat = ws + OFF_FEAT;
    float* agg  = ws + OFF_AGG;
    unsigned short* pmsg = (unsigned short*)(ws + OFF_PROJ);
    int*   slots = (int*)(ws + OFF_XBC);
    int*   cnt   = (int*)(ws + OFF_DTV);
    float* out  = (float*)d_out;

    hipMemsetAsync(feat, 0, (size_t)N_NODES_C * 16 * 4, stream);

    k_gather<<<(NROWS * 16 + 255) / 256, 256, 0, stream>>>(node_inputs, chk);
    k_fusew<<<(16 * DIP + DIP + DIN * 16 + 16 + 255) / 256, 256, 0, stream>>>(
        W_embed, b_embed, W_in, b_in, W_outp, b_outp, W_proj, b_proj, Wf, bf, Wop, bop);
    k_conv<<<dim3(2, 8, BATCH_C), 320, 0, stream>>>(chk, Wf, bf, conv_w, conv_b, xBCc, bbf);
    k_dte<<<(BATCH_C * NCHK * NH) / 4, 256, 0, stream>>>(chk, Wf, bf, A_log, dt_bias, dtv, ecum);
    k_scarry<<<dim3(NH, BATCH_C), 256, 0, stream>>>(xBCc, bbf, dtv, ecum, hst);
    k_intra<<<NCHK * NH * BATCH_C, 256, 0, stream>>>(xBCc, bbf, dtv, ecum, D_skip, hst);
    k_gate<<<NROWS / 8, 256, 0, stream>>>(chk, Wf, bf, xBCc, norm_w, Wop, bop, feat);
    hipMemsetAsync(cnt, 0, (size_t)N_NODES_C * 4, stream);
    k_scatter<<<(N_EDGES_C + 255) / 256, 256, 0, stream>>>(src_ids, dst_ids, cnt, slots);
    k_proj<<<N_NODES_C / 8, 256, 0, stream>>>(feat, W_msg, b_msg, pmsg);
    k_agg2<<<N_NODES_C / 4, 256, 0, stream>>>(cnt, slots, pmsg, agg);
    k_upd2<<<N_NODES_C / UNB, 256, 0, stream>>>(feat, agg, W_upd, b_upd, W_out, b_out, out);
}